// Round 5
// baseline (998.038 us; speedup 1.0000x reference)
//
#include <hip/hip_runtime.h>
#include <hip/hip_bf16.h>

// Problem constants
#define SHIFT_ 3
#define SCALE_ 0.17677669529663687f   // 32^-0.5
#define NTOK   200704                 // 64*56*56
#define NWIN   4096

typedef short v8s __attribute__((ext_vector_type(8)));
typedef float v4f __attribute__((ext_vector_type(4)));
#define MFMA16(a, b, c) __builtin_amdgcn_mfma_f32_16x16x32_bf16(a, b, c, 0, 0, 0)

static __device__ __forceinline__ unsigned short f2bf(float f) {
    union { float f; unsigned int u; } v; v.f = f;
    unsigned int u = v.u;
    unsigned int r = u + 0x7FFFu + ((u >> 16) & 1u);   // RNE
    return (unsigned short)(r >> 16);
}
static __device__ __forceinline__ float wsum(float v) {
    #pragma unroll
    for (int o = 32; o; o >>= 1) v += __shfl_xor(v, o);
    return v;
}
// tanh-form GELU in sigmoid shape: v*sigmoid(1.5957691*(v+0.044715 v^3)).
// Branch-free, ~8 VALU inst. |err vs exact| <~1e-3 at hidden pre-act scale.
static __device__ __forceinline__ float gelu_f(float v) {
    float w = v * v;
    float t = v * fmaf(w, 0.07135481283f, 1.595769122f);
    float e = __expf(-t);
    return v * __builtin_amdgcn_rcpf(1.f + e);
}

// ws layout (bytes):
//   0        : xw bf16 [4096 win][64 rows padded][128]   (later aliased by xn)
//   67108864 : comb f32 [64][4][64][64]
//   71303168 : wqkv bf16 [384][128]
//   71401472 : wproj bf16 [128][128]
//   71434240 : f1w bf16 [512][128]
//   71565312 : f2w bf16 [128][512]
#define WS_COMB  67108864
#define WS_WQKV  71303168
#define WS_WPROJ 71401472
#define WS_F1W   71434240
#define WS_F2W   71565312

// ---------------------------------------------------------------------------
// K0: prep — comb table, bf16 weight conversion, xw pad-row zeroing.
// ---------------------------------------------------------------------------
__global__ __launch_bounds__(256) void k_prep(
    const float* __restrict__ amask, const float* __restrict__ rbt,
    const int* __restrict__ relidx,
    const float* __restrict__ qkvw, const float* __restrict__ projw,
    const float* __restrict__ f1w, const float* __restrict__ f2w,
    float* __restrict__ comb, unsigned short* __restrict__ wqkv,
    unsigned short* __restrict__ wproj, unsigned short* __restrict__ f1wb,
    unsigned short* __restrict__ f2wb, unsigned short* __restrict__ xw) {
    int idx = blockIdx.x * 256 + threadIdx.x;
    if (idx < 1048576) {
        int wpos = idx >> 14;
        int h = (idx >> 12) & 3;
        int i = (idx >> 6) & 63;
        int j = idx & 63;
        float v;
        if (j >= 49) v = -1e30f;
        else if (i >= 49) v = 0.f;
        else v = amask[wpos * 2401 + i * 49 + j] + rbt[relidx[i * 49 + j] * 4 + h];
        comb[idx] = v;
    } else if (idx < 1048576 + 49152) {
        int k = idx - 1048576; wqkv[k] = f2bf(qkvw[k]);
    } else if (idx < 1048576 + 49152 + 16384) {
        int k = idx - (1048576 + 49152); wproj[k] = f2bf(projw[k]);
    } else if (idx < 1048576 + 49152 + 16384 + 65536) {
        int k = idx - (1048576 + 49152 + 16384); f1wb[k] = f2bf(f1w[k]);
    } else if (idx < 1048576 + 49152 + 16384 + 65536 + 65536) {
        int k = idx - (1048576 + 49152 + 16384 + 65536); f2wb[k] = f2bf(f2w[k]);
    } else {
        int k = idx - 1245184;          // 983,040 uint4 of pad rows
        if (k < 983040) {
            int win = k / 240, r = k - win * 240;
            uint4 z = make_uint4(0u, 0u, 0u, 0u);
            *(uint4*)((char*)xw + (size_t)win * 16384 + 12544 + (size_t)r * 16) = z;
        }
    }
}

// ---------------------------------------------------------------------------
// K1: LN1 + roll(-3,-3) + window partition -> xw [win][64(pad)][128] bf16.
// ---------------------------------------------------------------------------
__global__ __launch_bounds__(256) void k_ln1(const float* __restrict__ x,
                                             const float* __restrict__ nw,
                                             const float* __restrict__ nb,
                                             unsigned short* __restrict__ xw) {
    int tok  = blockIdx.x * 4 + (threadIdx.x >> 6);
    int lane = threadIdx.x & 63;
    int win = tok / 49, t = tok - win * 49;
    int bb = win >> 6, wh = (win >> 3) & 7, ww = win & 7;
    int i = t / 7, j = t - i * 7;
    int h  = wh * 7 + i + SHIFT_; if (h  >= 56) h  -= 56;
    int w2 = ww * 7 + j + SHIFT_; if (w2 >= 56) w2 -= 56;
    const float* src = x + ((size_t)bb * 3136 + h * 56 + w2) * 128;
    float v0 = src[lane], v1 = src[lane + 64];
    float mu = wsum(v0 + v1) * (1.f / 128.f);
    float d0 = v0 - mu, d1 = v1 - mu;
    float var = wsum(d0 * d0 + d1 * d1) * (1.f / 128.f);
    float inv = rsqrtf(var + 1e-5f);
    unsigned short* dst = xw + (size_t)win * 8192 + t * 128;
    dst[lane]      = f2bf(d0 * inv * nw[lane]      + nb[lane]);
    dst[lane + 64] = f2bf(d1 * inv * nw[lane + 64] + nb[lane + 64]);
}

// ---------------------------------------------------------------------------
// K3: LN2 over x2 (= d_out after attention) -> xn bf16 [tok][128].
// ---------------------------------------------------------------------------
__global__ __launch_bounds__(256) void k_ln2(const float* __restrict__ x2,
                                             const float* __restrict__ nw,
                                             const float* __restrict__ nb,
                                             unsigned short* __restrict__ xn) {
    int tok  = blockIdx.x * 4 + (threadIdx.x >> 6);
    int lane = threadIdx.x & 63;
    const float* src = x2 + (size_t)tok * 128;
    float v0 = src[lane], v1 = src[lane + 64];
    float mu = wsum(v0 + v1) * (1.f / 128.f);
    float d0 = v0 - mu, d1 = v1 - mu;
    float var = wsum(d0 * d0 + d1 * d1) * (1.f / 128.f);
    float inv = rsqrtf(var + 1e-5f);
    unsigned short* dst = xn + (size_t)tok * 128;
    dst[lane]      = f2bf(d0 * inv * nw[lane]      + nb[lane]);
    dst[lane + 64] = f2bf(d1 * inv * nw[lane + 64] + nb[lane + 64]);
}

// ---------------------------------------------------------------------------
// K2: MFMA window attention, pass body templated on KA (K-chunks = KA, Ca=32*KA).
// Round-0 structure (2 blocks/CU). Head loop FULLY unrolled so oacc/sc are
// compile-time indexed (no scratch). comb read per-head from global (L2-hot).
// ---------------------------------------------------------------------------
template<int KA>
__device__ __forceinline__ void attn_pass(
    const v8s (&ax)[4][4],
    const unsigned short* __restrict__ wqkv, const float* __restrict__ qkvb,
    const float* __restrict__ comb,
    const unsigned short* __restrict__ wproj, const float* __restrict__ pbias,
    float wgt, int wpos, int wv, int li, int lg,
    unsigned short* __restrict__ s_q, unsigned short* __restrict__ s_k,
    unsigned short* __restrict__ s_v, unsigned short* __restrict__ pw_,
    v4f (&yacc)[2][4])
{
    const v4f z4 = {0.f, 0.f, 0.f, 0.f};
    constexpr int Ca = KA * 32;

    // ---- QKV (n-split): wave handles cols [wv*96, wv*96+96) of 384 ----
    #pragma unroll 2
    for (int nt = 0; nt < 6; nt++) {
        const int ntg = wv * 6 + nt, o0 = ntg * 16;
        v4f acc[4] = {z4, z4, z4, z4};
        #pragma unroll
        for (int k = 0; k < KA; k++) {
            v8s b = *(const v8s*)(wqkv + (o0 + li) * 128 + k * 32 + lg * 8);
            #pragma unroll
            for (int m = 0; m < 4; m++) acc[m] = MFMA16(ax[m][k], b, acc[m]);
        }
        float bo = qkvb[o0 + li];
        if (ntg < 16) {              // q or k, token-major [64][136]
            unsigned short* dst = (ntg < 8) ? s_q : s_k;
            const int oc = (ntg < 8) ? o0 : o0 - 128;
            const float scl = (ntg < 8) ? SCALE_ : 1.f;
            #pragma unroll
            for (int m = 0; m < 4; m++)
                #pragma unroll
                for (int r = 0; r < 4; r++)
                    dst[(m * 16 + lg * 4 + r) * 136 + oc + li] =
                        f2bf((acc[m][r] + bo) * scl);
        } else {                     // v transposed: vT[d][t], [128][72]
            const int d = (ntg - 16) * 16 + li;
            #pragma unroll
            for (int m = 0; m < 4; m++) {
                int t0_ = m * 16 + lg * 4;
                unsigned int p0 = (unsigned int)f2bf(acc[m][0] + bo) |
                                  ((unsigned int)f2bf(acc[m][1] + bo) << 16);
                unsigned int p1 = (unsigned int)f2bf(acc[m][2] + bo) |
                                  ((unsigned int)f2bf(acc[m][3] + bo) << 16);
                *(unsigned int*)(s_v + d * 72 + t0_)     = p0;
                *(unsigned int*)(s_v + d * 72 + t0_ + 2) = p1;
            }
        }
    }
    __syncthreads();   // s1: q,k,vT visible

    // ---- heads (m-split): wave owns query rows [wv*16, wv*16+16) ----
    // FULL unroll: all array indices compile-time -> registers, no scratch.
    v4f oacc[8];
    #pragma unroll
    for (int i = 0; i < 8; i++) oacc[i] = z4;
    #pragma unroll
    for (int h = 0; h < 4; h++) {
        v8s aq = *(const v8s*)(s_q + (wv * 16 + li) * 136 + h * 32 + lg * 8);
        v4f sc[4];
        #pragma unroll
        for (int ntj = 0; ntj < 4; ntj++) {
            v8s bk = *(const v8s*)(s_k + (ntj * 16 + li) * 136 + h * 32 + lg * 8);
            sc[ntj] = MFMA16(aq, bk, z4);
        }
        const float* cb = comb + ((size_t)(wpos * 4 + h) << 12) + (wv * 16 + lg * 4) * 64;
        #pragma unroll
        for (int r = 0; r < 4; r++) {
            float vmax = -3.0e38f, e[4];
            #pragma unroll
            for (int ntj = 0; ntj < 4; ntj++) {
                float v_ = sc[ntj][r] + cb[r * 64 + ntj * 16 + li];
                sc[ntj][r] = v_;
                vmax = fmaxf(vmax, v_);
            }
            #pragma unroll
            for (int o_ = 1; o_ < 16; o_ <<= 1) vmax = fmaxf(vmax, __shfl_xor(vmax, o_));
            float ssum = 0.f;
            #pragma unroll
            for (int ntj = 0; ntj < 4; ntj++) {
                e[ntj] = __expf(sc[ntj][r] - vmax);
                ssum += e[ntj];
            }
            #pragma unroll
            for (int o_ = 1; o_ < 16; o_ <<= 1) ssum += __shfl_xor(ssum, o_);
            float inv = __builtin_amdgcn_rcpf(ssum);
            #pragma unroll
            for (int ntj = 0; ntj < 4; ntj++)
                pw_[(lg * 4 + r) * 72 + ntj * 16 + li] = f2bf(e[ntj] * inv);
        }
        // PV: O[t][h*32+d] += P @ V   (h, k0, dn all compile-time)
        #pragma unroll
        for (int k0 = 0; k0 < 2; k0++) {
            v8s ap = *(const v8s*)(pw_ + li * 72 + k0 * 32 + lg * 8);
            #pragma unroll
            for (int dn = 0; dn < 2; dn++) {
                v8s bv = *(const v8s*)(s_v + (h * 32 + dn * 16 + li) * 72 + k0 * 32 + lg * 8);
                oacc[h * 2 + dn] = MFMA16(ap, bv, oacc[h * 2 + dn]);
            }
        }
    }
    __syncthreads();   // s2: all waves done reading s_k/s_v/s_q

    // ---- o -> LDS (reuse s_k region), token-major [64][136] ----
    unsigned short* s_o = s_k;
    #pragma unroll
    for (int ot = 0; ot < 8; ot++)
        #pragma unroll
        for (int r = 0; r < 4; r++)
            s_o[(wv * 16 + lg * 4 + r) * 136 + ot * 16 + li] = f2bf(oacc[ot][r]);
    __syncthreads();   // s3: o visible

    // ---- proj (n-split, interleaved tiles (nt*4+wv)*16, compile-time mask) ----
    if (KA == 4 || wv * 16 < Ca) {
        v8s ao[4][4];
        #pragma unroll
        for (int m = 0; m < 4; m++)
            #pragma unroll
            for (int k = 0; k < 4; k++)
                ao[m][k] = *(const v8s*)(s_o + (m * 16 + li) * 136 + k * 32 + lg * 8);
        #pragma unroll
        for (int nt = 0; nt < 2; nt++) {
            const int co0 = (nt * 4 + wv) * 16;
            if (nt == 0 || Ca == 128) {
                if (co0 < Ca) {
                    v4f pacc[4] = {z4, z4, z4, z4};
                    #pragma unroll
                    for (int k = 0; k < 4; k++) {
                        v8s b = *(const v8s*)(wproj + (co0 + li) * 128 + k * 32 + lg * 8);
                        #pragma unroll
                        for (int m = 0; m < 4; m++) pacc[m] = MFMA16(ao[m][k], b, pacc[m]);
                    }
                    float bo = pbias[co0 + li];
                    #pragma unroll
                    for (int m = 0; m < 4; m++)
                        #pragma unroll
                        for (int r = 0; r < 4; r++)
                            yacc[nt][m][r] += wgt * (pacc[m][r] + bo);
                }
            }
        }
    }
    __syncthreads();   // s4: end of pass (protects s_q/s_k/s_v reuse)
}

__global__ __launch_bounds__(256, 2) void k_attn(
    const unsigned short* __restrict__ xw,
    const unsigned short* __restrict__ wqkv, const float* __restrict__ qkvb,
    const float* __restrict__ comb,
    const unsigned short* __restrict__ wproj, const float* __restrict__ pbias,
    const float* __restrict__ gw,
    const float* __restrict__ x, float* __restrict__ out) {

    __shared__ unsigned short sm[31232];
    unsigned short* s_q = sm;            // [64][136]
    unsigned short* s_k = sm + 8704;     // [64][136], later o
    unsigned short* s_v = sm + 17408;    // vT [128][72]
    unsigned short* s_p = sm + 26624;    // 4 x [16][72]

    const int tid = threadIdx.x, wv = tid >> 6, lane = tid & 63;
    const int li = lane & 15, lg = lane >> 4;
    const int w = blockIdx.x;
    const int wpos = w & 63;
    const bool sp = (w >= 2048);
    const unsigned short* xwin = xw + (size_t)w * 8192;
    unsigned short* pw_ = s_p + wv * 1152;

    const v4f z4 = {0.f, 0.f, 0.f, 0.f};
    v4f yacc[2][4];
    #pragma unroll
    for (int n = 0; n < 2; n++)
        #pragma unroll
        for (int m = 0; m < 4; m++) yacc[n][m] = z4;

    // A-fragments of x (pass-invariant): load once
    v8s ax[4][4];
    #pragma unroll
    for (int m = 0; m < 4; m++)
        #pragma unroll
        for (int k = 0; k < 4; k++)
            ax[m][k] = *(const v8s*)(xwin + (m * 16 + li) * 128 + k * 32 + lg * 8);

    if (sp) {
        attn_pass<4>(ax, wqkv, qkvb, comb, wproj, pbias, gw[0], wpos, wv, li, lg,
                     s_q, s_k, s_v, pw_, yacc);
        attn_pass<2>(ax, wqkv, qkvb, comb, wproj, pbias, gw[1], wpos, wv, li, lg,
                     s_q, s_k, s_v, pw_, yacc);
        attn_pass<1>(ax, wqkv, qkvb, comb, wproj, pbias, gw[2], wpos, wv, li, lg,
                     s_q, s_k, s_v, pw_, yacc);
    } else {
        attn_pass<4>(ax, wqkv, qkvb, comb, wproj, pbias, 1.f, wpos, wv, li, lg,
                     s_q, s_k, s_v, pw_, yacc);
    }

    // ---- epilogue: stage y in LDS, then coalesced window-reverse+roll+residual
    // (s4 barrier at end of last pass makes sm reusable here)
    float* s_y = (float*)sm;             // [64][132] f32 = 33,792 B
    #pragma unroll
    for (int m = 0; m < 4; m++)
        #pragma unroll
        for (int r = 0; r < 4; r++) {
            int t = m * 16 + lg * 4 + r;
            #pragma unroll
            for (int nt = 0; nt < 2; nt++)
                s_y[t * 132 + (nt * 4 + wv) * 16 + li] = yacc[nt][m][r];
        }
    __syncthreads();

    const int bb = w >> 6, wh = (w >> 3) & 7, ww = w & 7;
    const int rgrp = tid >> 5;           // 0..7
    const int col  = (tid & 31) * 4;     // 0..124
    #pragma unroll
    for (int it = 0; it < 7; it++) {
        int t = it * 8 + rgrp;
        if (t < 49) {
            int ti = t / 7, tj = t - ti * 7;
            int h2 = wh * 7 + ti + SHIFT_; if (h2 >= 56) h2 -= 56;
            int w2 = ww * 7 + tj + SHIFT_; if (w2 >= 56) w2 -= 56;
            size_t base = ((size_t)bb * 3136 + h2 * 56 + w2) * 128 + col;
            v4f xv = *(const v4f*)(x + base);
            v4f yv = *(const v4f*)(s_y + t * 132 + col);
            *(v4f*)(out + base) = xv + yv;
        }
    }
}

// ---------------------------------------------------------------------------
// K4: MFMA MLP, 64 tokens per block, 512 threads (8 waves).
// fc1: wave owns 64 hidden cols (4 n-tiles), M=64 (4 m-frags).
// fc2: wave owns ONE 16-col output tile over K=512 (16 b-loads, 64 MFMA).
// s_h [64][512] bf16 = 64 KiB -> 2 blocks/CU; swizzled 16-B chunks.
// Weight L2 traffic halves vs 32-token blocks; 4 MFMA per fc2 b-load.
// ---------------------------------------------------------------------------
template<int KA>
__device__ __forceinline__ void mlp_pass(
    const unsigned short* __restrict__ xn, int t0,
    const unsigned short* __restrict__ f1wb, const float* __restrict__ f1b,
    const unsigned short* __restrict__ f2wb, const float* __restrict__ f2b,
    float wgt, int wv, int li, int lg,
    unsigned short* __restrict__ s_h, v4f (&yacc)[4])
{
    const v4f z4 = {0.f, 0.f, 0.f, 0.f};
    constexpr int Ca = KA * 32;

    // ---- fc1 + GELU -> s_h. A-fragments scoped here (dead before fc2). ----
    {
        v8s ax[4][KA];     // only the first KA*32 input channels are live
        #pragma unroll
        for (int m = 0; m < 4; m++)
            #pragma unroll
            for (int k = 0; k < KA; k++)
                ax[m][k] = *(const v8s*)(xn + (size_t)(t0 + m * 16 + li) * 128 + k * 32 + lg * 8);

        #pragma unroll
        for (int nt = 0; nt < 4; nt++) {
            const int o0 = wv * 64 + nt * 16;
            v4f acc[4] = {z4, z4, z4, z4};
            #pragma unroll
            for (int k = 0; k < KA; k++) {
                v8s b = *(const v8s*)(f1wb + (o0 + li) * 128 + k * 32 + lg * 8);
                #pragma unroll
                for (int m = 0; m < 4; m++) acc[m] = MFMA16(ax[m][k], b, acc[m]);
            }
            float bo = f1b[o0 + li];
            const int chb = (o0 >> 3) + (li >> 3);   // = col>>3 (o0 mult of 16)
            const int clo = li & 7;
            #pragma unroll
            for (int m = 0; m < 4; m++)
                #pragma unroll
                for (int r = 0; r < 4; r++) {
                    float g = gelu_f(acc[m][r] + bo);
                    int row = m * 16 + lg * 4 + r;
                    s_h[row * 512 + ((chb ^ (row & 7)) << 3) + clo] = f2bf(g);
                }
        }
    }
    __syncthreads();   // s_h visible

    // ---- fc2: out tile c0 = wv*16, masked by Ca at compile/run time ----
    if (KA == 4 || wv * 16 < Ca) {
        const int c0 = wv * 16;
        v4f acc2[4] = {z4, z4, z4, z4};
        #pragma unroll
        for (int k = 0; k < 16; k++) {
            const int sw = ((4 * k + lg) ^ (li & 7)) << 3;
            v8s b0 = *(const v8s*)(f2wb + (c0 + li) * 512 + k * 32 + lg * 8);
            #pragma unroll
            for (int m = 0; m < 4; m++) {
                v8s a = *(const v8s*)(s_h + (m * 16 + li) * 512 + sw);
                acc2[m] = MFMA16(a, b0, acc2[m]);
            }
        }
        float bo = f2b[c0 + li];
        #pragma unroll
        for (int m = 0; m < 4; m++)
            #pragma unroll
            for (int r = 0; r < 4; r++)
                yacc[m][r] += wgt * (acc2[m][r] + bo);
    }
}

__global__ __launch_bounds__(512, 4) void k_mlp(
    const unsigned short* __restrict__ xn,
    const unsigned short* __restrict__ f1wb, const float* __restrict__ f1b,
    const unsigned short* __restrict__ f2wb, const float* __restrict__ f2b,
    const float* __restrict__ gw, float* __restrict__ out) {

    __shared__ unsigned short s_h[64 * 512];   // 65,536 B -> 2 blocks/CU

    const int tid = threadIdx.x, wv = tid >> 6, lane = tid & 63;
    const int li = lane & 15, lg = lane >> 4;
    const int t0 = blockIdx.x * 64;
    const bool sp = (t0 >= 100352);

    const v4f z4 = {0.f, 0.f, 0.f, 0.f};
    v4f yacc[4] = {z4, z4, z4, z4};

    if (sp) {
        mlp_pass<4>(xn, t0, f1wb, f1b, f2wb, f2b, gw[0], wv, li, lg, s_h, yacc);
        __syncthreads();   // protect s_h overwrite vs fc2 reads
        mlp_pass<2>(xn, t0, f1wb, f1b, f2wb, f2b, gw[1], wv, li, lg, s_h, yacc);
        __syncthreads();
        mlp_pass<1>(xn, t0, f1wb, f1b, f2wb, f2b, gw[2], wv, li, lg, s_h, yacc);
    } else {
        mlp_pass<4>(xn, t0, f1wb, f1b, f2wb, f2b, 1.f, wv, li, lg, s_h, yacc);
    }

    // ---- epilogue: stage y in LDS, then coalesced out += y ----
    __syncthreads();                     // fc2 reads of s_h complete
    float* s_y = (float*)s_h;            // [64][132] f32 = 33,792 B < 64 KiB
    #pragma unroll
    for (int m = 0; m < 4; m++)
        #pragma unroll
        for (int r = 0; r < 4; r++)
            s_y[(m * 16 + lg * 4 + r) * 132 + wv * 16 + li] = yacc[m][r];
    __syncthreads();

    const int rgrp = tid >> 5;           // 0..15
    const int col  = (tid & 31) * 4;     // 0..124
    #pragma unroll
    for (int it = 0; it < 4; it++) {
        int t = it * 16 + rgrp;
        size_t base = (size_t)(t0 + t) * 128 + col;
        v4f ov = *(const v4f*)(out + base);
        v4f yv = *(const v4f*)(s_y + t * 132 + col);
        *(v4f*)(out + base) = ov + yv;
    }
}

// ---------------------------------------------------------------------------
extern "C" void kernel_launch(void* const* d_in, const int* in_sizes, int n_in,
                              void* d_out, int out_size, void* d_ws, size_t ws_size,
                              hipStream_t stream) {
    const float* x      = (const float*)d_in[0];
    const float* gw     = (const float*)d_in[1];
    const float* n1w    = (const float*)d_in[2];
    const float* n1b    = (const float*)d_in[3];
    const float* qkvw   = (const float*)d_in[4];
    const float* qkvb   = (const float*)d_in[5];
    const float* rbt    = (const float*)d_in[6];
    const float* pw     = (const float*)d_in[7];
    const float* pb     = (const float*)d_in[8];
    const float* amask  = (const float*)d_in[9];
    const float* n2w    = (const float*)d_in[10];
    const float* n2b    = (const float*)d_in[11];
    const float* f1w    = (const float*)d_in[12];
    const float* f1b    = (const float*)d_in[13];
    const float* f2w    = (const float*)d_in[14];
    const float* f2b    = (const float*)d_in[15];
    const int*   relidx = (const int*)d_in[16];
    float* out = (float*)d_out;

    unsigned short* xw    = (unsigned short*)d_ws;
    float*          comb  = (float*)((char*)d_ws + WS_COMB);
    unsigned short* wqkv  = (unsigned short*)((char*)d_ws + WS_WQKV);
    unsigned short* wproj = (unsigned short*)((char*)d_ws + WS_WPROJ);
    unsigned short* f1wb  = (unsigned short*)((char*)d_ws + WS_F1W);
    unsigned short* f2wb  = (unsigned short*)((char*)d_ws + WS_F2W);
    unsigned short* xn    = (unsigned short*)d_ws;   // aliases xw (dead by then)

    hipLaunchKernelGGL(k_prep, dim3(8704), dim3(256), 0, stream,
                       amask, rbt, relidx, qkvw, pw, f1w, f2w,
                       comb, wqkv, wproj, f1wb, f2wb, xw);
    hipLaunchKernelGGL(k_ln1, dim3(NTOK / 4), dim3(256), 0, stream, x, n1w, n1b, xw);
    hipLaunchKernelGGL(k_attn, dim3(NWIN), dim3(256), 0, stream,
                       xw, wqkv, qkvb, comb, wproj, pb, gw, x, out);
    hipLaunchKernelGGL(k_ln2, dim3(NTOK / 4), dim3(256), 0, stream, out, n2w, n2b, xn);
    hipLaunchKernelGGL(k_mlp, dim3(NTOK / 64), dim3(512), 0, stream,
                       xn, f1wb, f1b, f2wb, f2b, gw, out);
}

// Round 6
// 778.508 us; speedup vs baseline: 1.2820x; 1.2820x over previous
//
#include <hip/hip_runtime.h>
#include <hip/hip_bf16.h>

// Problem constants
#define SHIFT_ 3
#define SCALE_ 0.17677669529663687f   // 32^-0.5
#define NTOK   200704                 // 64*56*56
#define NWIN   4096

typedef short v8s __attribute__((ext_vector_type(8)));
typedef float v4f __attribute__((ext_vector_type(4)));
#define MFMA16(a, b, c) __builtin_amdgcn_mfma_f32_16x16x32_bf16(a, b, c, 0, 0, 0)

static __device__ __forceinline__ unsigned short f2bf(float f) {
    union { float f; unsigned int u; } v; v.f = f;
    unsigned int u = v.u;
    unsigned int r = u + 0x7FFFu + ((u >> 16) & 1u);   // RNE
    return (unsigned short)(r >> 16);
}
static __device__ __forceinline__ float wsum(float v) {
    #pragma unroll
    for (int o = 32; o; o >>= 1) v += __shfl_xor(v, o);
    return v;
}
// tanh-form GELU in sigmoid shape: v*sigmoid(1.5957691*(v+0.044715 v^3)).
// Branch-free, ~8 VALU inst. |err vs exact| <~1e-3 at hidden pre-act scale.
static __device__ __forceinline__ float gelu_f(float v) {
    float w = v * v;
    float t = v * fmaf(w, 0.07135481283f, 1.595769122f);
    float e = __expf(-t);
    return v * __builtin_amdgcn_rcpf(1.f + e);
}

// ws layout (bytes):
//   0        : xw bf16 [4096 win][64 rows padded][128]   (later aliased by xn)
//   67108864 : comb f32 [64][4][64][64]
//   71303168 : wqkv bf16 [384][128]
//   71401472 : wproj bf16 [128][128]
//   71434240 : f1w bf16 [512][128]
//   71565312 : f2w bf16 [128][512]
#define WS_COMB  67108864
#define WS_WQKV  71303168
#define WS_WPROJ 71401472
#define WS_F1W   71434240
#define WS_F2W   71565312

// ---------------------------------------------------------------------------
// K0: prep — comb table, bf16 weight conversion, xw pad-row zeroing.
// ---------------------------------------------------------------------------
__global__ __launch_bounds__(256) void k_prep(
    const float* __restrict__ amask, const float* __restrict__ rbt,
    const int* __restrict__ relidx,
    const float* __restrict__ qkvw, const float* __restrict__ projw,
    const float* __restrict__ f1w, const float* __restrict__ f2w,
    float* __restrict__ comb, unsigned short* __restrict__ wqkv,
    unsigned short* __restrict__ wproj, unsigned short* __restrict__ f1wb,
    unsigned short* __restrict__ f2wb, unsigned short* __restrict__ xw) {
    int idx = blockIdx.x * 256 + threadIdx.x;
    if (idx < 1048576) {
        int wpos = idx >> 14;
        int h = (idx >> 12) & 3;
        int i = (idx >> 6) & 63;
        int j = idx & 63;
        float v;
        if (j >= 49) v = -1e30f;
        else if (i >= 49) v = 0.f;
        else v = amask[wpos * 2401 + i * 49 + j] + rbt[relidx[i * 49 + j] * 4 + h];
        comb[idx] = v;
    } else if (idx < 1048576 + 49152) {
        int k = idx - 1048576; wqkv[k] = f2bf(qkvw[k]);
    } else if (idx < 1048576 + 49152 + 16384) {
        int k = idx - (1048576 + 49152); wproj[k] = f2bf(projw[k]);
    } else if (idx < 1048576 + 49152 + 16384 + 65536) {
        int k = idx - (1048576 + 49152 + 16384); f1wb[k] = f2bf(f1w[k]);
    } else if (idx < 1048576 + 49152 + 16384 + 65536 + 65536) {
        int k = idx - (1048576 + 49152 + 16384 + 65536); f2wb[k] = f2bf(f2w[k]);
    } else {
        int k = idx - 1245184;          // 983,040 uint4 of pad rows
        if (k < 983040) {
            int win = k / 240, r = k - win * 240;
            uint4 z = make_uint4(0u, 0u, 0u, 0u);
            *(uint4*)((char*)xw + (size_t)win * 16384 + 12544 + (size_t)r * 16) = z;
        }
    }
}

// ---------------------------------------------------------------------------
// K1: LN1 + roll(-3,-3) + window partition -> xw [win][64(pad)][128] bf16.
// ---------------------------------------------------------------------------
__global__ __launch_bounds__(256) void k_ln1(const float* __restrict__ x,
                                             const float* __restrict__ nw,
                                             const float* __restrict__ nb,
                                             unsigned short* __restrict__ xw) {
    int tok  = blockIdx.x * 4 + (threadIdx.x >> 6);
    int lane = threadIdx.x & 63;
    int win = tok / 49, t = tok - win * 49;
    int bb = win >> 6, wh = (win >> 3) & 7, ww = win & 7;
    int i = t / 7, j = t - i * 7;
    int h  = wh * 7 + i + SHIFT_; if (h  >= 56) h  -= 56;
    int w2 = ww * 7 + j + SHIFT_; if (w2 >= 56) w2 -= 56;
    const float* src = x + ((size_t)bb * 3136 + h * 56 + w2) * 128;
    float v0 = src[lane], v1 = src[lane + 64];
    float mu = wsum(v0 + v1) * (1.f / 128.f);
    float d0 = v0 - mu, d1 = v1 - mu;
    float var = wsum(d0 * d0 + d1 * d1) * (1.f / 128.f);
    float inv = rsqrtf(var + 1e-5f);
    unsigned short* dst = xw + (size_t)win * 8192 + t * 128;
    dst[lane]      = f2bf(d0 * inv * nw[lane]      + nb[lane]);
    dst[lane + 64] = f2bf(d1 * inv * nw[lane + 64] + nb[lane + 64]);
}

// ---------------------------------------------------------------------------
// K3: LN2 over x2 (= d_out after attention) -> xn bf16 [tok][128].
// ---------------------------------------------------------------------------
__global__ __launch_bounds__(256) void k_ln2(const float* __restrict__ x2,
                                             const float* __restrict__ nw,
                                             const float* __restrict__ nb,
                                             unsigned short* __restrict__ xn) {
    int tok  = blockIdx.x * 4 + (threadIdx.x >> 6);
    int lane = threadIdx.x & 63;
    const float* src = x2 + (size_t)tok * 128;
    float v0 = src[lane], v1 = src[lane + 64];
    float mu = wsum(v0 + v1) * (1.f / 128.f);
    float d0 = v0 - mu, d1 = v1 - mu;
    float var = wsum(d0 * d0 + d1 * d1) * (1.f / 128.f);
    float inv = rsqrtf(var + 1e-5f);
    unsigned short* dst = xn + (size_t)tok * 128;
    dst[lane]      = f2bf(d0 * inv * nw[lane]      + nb[lane]);
    dst[lane + 64] = f2bf(d1 * inv * nw[lane + 64] + nb[lane + 64]);
}

// ---------------------------------------------------------------------------
// K2: MFMA window attention, pass body templated on KA (K-chunks = KA, Ca=32*KA).
// Round-0 structure (2 blocks/CU). Head loop FULLY unrolled so oacc/sc are
// compile-time indexed (no scratch). comb read per-head from global (L2-hot).
// ---------------------------------------------------------------------------
template<int KA>
__device__ __forceinline__ void attn_pass(
    const v8s (&ax)[4][4],
    const unsigned short* __restrict__ wqkv, const float* __restrict__ qkvb,
    const float* __restrict__ comb,
    const unsigned short* __restrict__ wproj, const float* __restrict__ pbias,
    float wgt, int wpos, int wv, int li, int lg,
    unsigned short* __restrict__ s_q, unsigned short* __restrict__ s_k,
    unsigned short* __restrict__ s_v, unsigned short* __restrict__ pw_,
    v4f (&yacc)[2][4])
{
    const v4f z4 = {0.f, 0.f, 0.f, 0.f};
    constexpr int Ca = KA * 32;

    // ---- QKV (n-split): wave handles cols [wv*96, wv*96+96) of 384 ----
    #pragma unroll 2
    for (int nt = 0; nt < 6; nt++) {
        const int ntg = wv * 6 + nt, o0 = ntg * 16;
        v4f acc[4] = {z4, z4, z4, z4};
        #pragma unroll
        for (int k = 0; k < KA; k++) {
            v8s b = *(const v8s*)(wqkv + (o0 + li) * 128 + k * 32 + lg * 8);
            #pragma unroll
            for (int m = 0; m < 4; m++) acc[m] = MFMA16(ax[m][k], b, acc[m]);
        }
        float bo = qkvb[o0 + li];
        if (ntg < 16) {              // q or k, token-major [64][136]
            unsigned short* dst = (ntg < 8) ? s_q : s_k;
            const int oc = (ntg < 8) ? o0 : o0 - 128;
            const float scl = (ntg < 8) ? SCALE_ : 1.f;
            #pragma unroll
            for (int m = 0; m < 4; m++)
                #pragma unroll
                for (int r = 0; r < 4; r++)
                    dst[(m * 16 + lg * 4 + r) * 136 + oc + li] =
                        f2bf((acc[m][r] + bo) * scl);
        } else {                     // v transposed: vT[d][t], [128][72]
            const int d = (ntg - 16) * 16 + li;
            #pragma unroll
            for (int m = 0; m < 4; m++) {
                int t0_ = m * 16 + lg * 4;
                unsigned int p0 = (unsigned int)f2bf(acc[m][0] + bo) |
                                  ((unsigned int)f2bf(acc[m][1] + bo) << 16);
                unsigned int p1 = (unsigned int)f2bf(acc[m][2] + bo) |
                                  ((unsigned int)f2bf(acc[m][3] + bo) << 16);
                *(unsigned int*)(s_v + d * 72 + t0_)     = p0;
                *(unsigned int*)(s_v + d * 72 + t0_ + 2) = p1;
            }
        }
    }
    __syncthreads();   // s1: q,k,vT visible

    // ---- heads (m-split): wave owns query rows [wv*16, wv*16+16) ----
    // FULL unroll: all array indices compile-time -> registers, no scratch.
    v4f oacc[8];
    #pragma unroll
    for (int i = 0; i < 8; i++) oacc[i] = z4;
    #pragma unroll
    for (int h = 0; h < 4; h++) {
        v8s aq = *(const v8s*)(s_q + (wv * 16 + li) * 136 + h * 32 + lg * 8);
        v4f sc[4];
        #pragma unroll
        for (int ntj = 0; ntj < 4; ntj++) {
            v8s bk = *(const v8s*)(s_k + (ntj * 16 + li) * 136 + h * 32 + lg * 8);
            sc[ntj] = MFMA16(aq, bk, z4);
        }
        const float* cb = comb + ((size_t)(wpos * 4 + h) << 12) + (wv * 16 + lg * 4) * 64;
        #pragma unroll
        for (int r = 0; r < 4; r++) {
            float vmax = -3.0e38f, e[4];
            #pragma unroll
            for (int ntj = 0; ntj < 4; ntj++) {
                float v_ = sc[ntj][r] + cb[r * 64 + ntj * 16 + li];
                sc[ntj][r] = v_;
                vmax = fmaxf(vmax, v_);
            }
            #pragma unroll
            for (int o_ = 1; o_ < 16; o_ <<= 1) vmax = fmaxf(vmax, __shfl_xor(vmax, o_));
            float ssum = 0.f;
            #pragma unroll
            for (int ntj = 0; ntj < 4; ntj++) {
                e[ntj] = __expf(sc[ntj][r] - vmax);
                ssum += e[ntj];
            }
            #pragma unroll
            for (int o_ = 1; o_ < 16; o_ <<= 1) ssum += __shfl_xor(ssum, o_);
            float inv = __builtin_amdgcn_rcpf(ssum);
            #pragma unroll
            for (int ntj = 0; ntj < 4; ntj++)
                pw_[(lg * 4 + r) * 72 + ntj * 16 + li] = f2bf(e[ntj] * inv);
        }
        // PV: O[t][h*32+d] += P @ V   (h, k0, dn all compile-time)
        #pragma unroll
        for (int k0 = 0; k0 < 2; k0++) {
            v8s ap = *(const v8s*)(pw_ + li * 72 + k0 * 32 + lg * 8);
            #pragma unroll
            for (int dn = 0; dn < 2; dn++) {
                v8s bv = *(const v8s*)(s_v + (h * 32 + dn * 16 + li) * 72 + k0 * 32 + lg * 8);
                oacc[h * 2 + dn] = MFMA16(ap, bv, oacc[h * 2 + dn]);
            }
        }
    }
    __syncthreads();   // s2: all waves done reading s_k/s_v/s_q

    // ---- o -> LDS (reuse s_k region), token-major [64][136] ----
    unsigned short* s_o = s_k;
    #pragma unroll
    for (int ot = 0; ot < 8; ot++)
        #pragma unroll
        for (int r = 0; r < 4; r++)
            s_o[(wv * 16 + lg * 4 + r) * 136 + ot * 16 + li] = f2bf(oacc[ot][r]);
    __syncthreads();   // s3: o visible

    // ---- proj (n-split, interleaved tiles (nt*4+wv)*16, compile-time mask) ----
    if (KA == 4 || wv * 16 < Ca) {
        v8s ao[4][4];
        #pragma unroll
        for (int m = 0; m < 4; m++)
            #pragma unroll
            for (int k = 0; k < 4; k++)
                ao[m][k] = *(const v8s*)(s_o + (m * 16 + li) * 136 + k * 32 + lg * 8);
        #pragma unroll
        for (int nt = 0; nt < 2; nt++) {
            const int co0 = (nt * 4 + wv) * 16;
            if (nt == 0 || Ca == 128) {
                if (co0 < Ca) {
                    v4f pacc[4] = {z4, z4, z4, z4};
                    #pragma unroll
                    for (int k = 0; k < 4; k++) {
                        v8s b = *(const v8s*)(wproj + (co0 + li) * 128 + k * 32 + lg * 8);
                        #pragma unroll
                        for (int m = 0; m < 4; m++) pacc[m] = MFMA16(ao[m][k], b, pacc[m]);
                    }
                    float bo = pbias[co0 + li];
                    #pragma unroll
                    for (int m = 0; m < 4; m++)
                        #pragma unroll
                        for (int r = 0; r < 4; r++)
                            yacc[nt][m][r] += wgt * (pacc[m][r] + bo);
                }
            }
        }
    }
    __syncthreads();   // s4: end of pass (protects s_q/s_k/s_v reuse)
}

__global__ __launch_bounds__(256, 2) void k_attn(
    const unsigned short* __restrict__ xw,
    const unsigned short* __restrict__ wqkv, const float* __restrict__ qkvb,
    const float* __restrict__ comb,
    const unsigned short* __restrict__ wproj, const float* __restrict__ pbias,
    const float* __restrict__ gw,
    const float* __restrict__ x, float* __restrict__ out) {

    __shared__ unsigned short sm[31232];
    unsigned short* s_q = sm;            // [64][136]
    unsigned short* s_k = sm + 8704;     // [64][136], later o
    unsigned short* s_v = sm + 17408;    // vT [128][72]
    unsigned short* s_p = sm + 26624;    // 4 x [16][72]

    const int tid = threadIdx.x, wv = tid >> 6, lane = tid & 63;
    const int li = lane & 15, lg = lane >> 4;
    const int w = blockIdx.x;
    const int wpos = w & 63;
    const bool sp = (w >= 2048);
    const unsigned short* xwin = xw + (size_t)w * 8192;
    unsigned short* pw_ = s_p + wv * 1152;

    const v4f z4 = {0.f, 0.f, 0.f, 0.f};
    v4f yacc[2][4];
    #pragma unroll
    for (int n = 0; n < 2; n++)
        #pragma unroll
        for (int m = 0; m < 4; m++) yacc[n][m] = z4;

    // A-fragments of x (pass-invariant): load once
    v8s ax[4][4];
    #pragma unroll
    for (int m = 0; m < 4; m++)
        #pragma unroll
        for (int k = 0; k < 4; k++)
            ax[m][k] = *(const v8s*)(xwin + (m * 16 + li) * 128 + k * 32 + lg * 8);

    if (sp) {
        attn_pass<4>(ax, wqkv, qkvb, comb, wproj, pbias, gw[0], wpos, wv, li, lg,
                     s_q, s_k, s_v, pw_, yacc);
        attn_pass<2>(ax, wqkv, qkvb, comb, wproj, pbias, gw[1], wpos, wv, li, lg,
                     s_q, s_k, s_v, pw_, yacc);
        attn_pass<1>(ax, wqkv, qkvb, comb, wproj, pbias, gw[2], wpos, wv, li, lg,
                     s_q, s_k, s_v, pw_, yacc);
    } else {
        attn_pass<4>(ax, wqkv, qkvb, comb, wproj, pbias, 1.f, wpos, wv, li, lg,
                     s_q, s_k, s_v, pw_, yacc);
    }

    // ---- epilogue: stage y in LDS, then coalesced window-reverse+roll+residual
    // (s4 barrier at end of last pass makes sm reusable here)
    float* s_y = (float*)sm;             // [64][132] f32 = 33,792 B
    #pragma unroll
    for (int m = 0; m < 4; m++)
        #pragma unroll
        for (int r = 0; r < 4; r++) {
            int t = m * 16 + lg * 4 + r;
            #pragma unroll
            for (int nt = 0; nt < 2; nt++)
                s_y[t * 132 + (nt * 4 + wv) * 16 + li] = yacc[nt][m][r];
        }
    __syncthreads();

    const int bb = w >> 6, wh = (w >> 3) & 7, ww = w & 7;
    const int rgrp = tid >> 5;           // 0..7
    const int col  = (tid & 31) * 4;     // 0..124
    #pragma unroll
    for (int it = 0; it < 7; it++) {
        int t = it * 8 + rgrp;
        if (t < 49) {
            int ti = t / 7, tj = t - ti * 7;
            int h2 = wh * 7 + ti + SHIFT_; if (h2 >= 56) h2 -= 56;
            int w2 = ww * 7 + tj + SHIFT_; if (w2 >= 56) w2 -= 56;
            size_t base = ((size_t)bb * 3136 + h2 * 56 + w2) * 128 + col;
            v4f xv = *(const v4f*)(x + base);
            v4f yv = *(const v4f*)(s_y + t * 132 + col);
            *(v4f*)(out + base) = xv + yv;
        }
    }
}

// ---------------------------------------------------------------------------
// K4: MFMA MLP, pass body templated on KA. One block (4 waves) per 32 tokens.
// R3-verified allocation point (VGPR 64, zero spill); only GELU swapped.
// ---------------------------------------------------------------------------
template<int KA>
__device__ __forceinline__ void mlp_pass(
    const v8s (&ax)[2][4],
    const unsigned short* __restrict__ f1wb, const float* __restrict__ f1b,
    const unsigned short* __restrict__ f2wb, const float* __restrict__ f2b,
    float wgt, int wv, int li, int lg,
    unsigned short* __restrict__ s_h, v4f (&yacc)[2][2])
{
    const v4f z4 = {0.f, 0.f, 0.f, 0.f};
    constexpr int Ca = KA * 32;

    // fc1 (n-split: wave cols [wv*128, wv*128+128)) + GELU -> s_h bf16
    #pragma unroll 4
    for (int nt = 0; nt < 8; nt++) {
        const int o0 = wv * 128 + nt * 16;
        v4f acc[2] = {z4, z4};
        #pragma unroll
        for (int k = 0; k < KA; k++) {
            v8s b = *(const v8s*)(f1wb + (o0 + li) * 128 + k * 32 + lg * 8);
            acc[0] = MFMA16(ax[0][k], b, acc[0]);
            acc[1] = MFMA16(ax[1][k], b, acc[1]);
        }
        float bo = f1b[o0 + li];
        #pragma unroll
        for (int m = 0; m < 2; m++)
            #pragma unroll
            for (int r = 0; r < 4; r++) {
                float v_ = gelu_f(acc[m][r] + bo);
                s_h[(m * 16 + lg * 4 + r) * 520 + o0 + li] = f2bf(v_);
            }
    }
    __syncthreads();

    // fc2: tiles co0 = wv*16 and 64+wv*16, compile-time masked, K=512 unrolled
    if (KA == 4) {
        const int c0 = wv * 16, c1 = 64 + wv * 16;
        v4f acc2[2][2] = {{z4, z4}, {z4, z4}};
        #pragma unroll
        for (int k = 0; k < 16; k++) {
            v8s a0 = *(const v8s*)(s_h + li * 520 + k * 32 + lg * 8);
            v8s a1 = *(const v8s*)(s_h + (16 + li) * 520 + k * 32 + lg * 8);
            v8s b0 = *(const v8s*)(f2wb + (c0 + li) * 512 + k * 32 + lg * 8);
            v8s b1 = *(const v8s*)(f2wb + (c1 + li) * 512 + k * 32 + lg * 8);
            acc2[0][0] = MFMA16(a0, b0, acc2[0][0]);
            acc2[0][1] = MFMA16(a1, b0, acc2[0][1]);
            acc2[1][0] = MFMA16(a0, b1, acc2[1][0]);
            acc2[1][1] = MFMA16(a1, b1, acc2[1][1]);
        }
        float bo0 = f2b[c0 + li], bo1 = f2b[c1 + li];
        #pragma unroll
        for (int m = 0; m < 2; m++)
            #pragma unroll
            for (int r = 0; r < 4; r++) {
                yacc[0][m][r] += wgt * (acc2[0][m][r] + bo0);
                yacc[1][m][r] += wgt * (acc2[1][m][r] + bo1);
            }
    } else if (KA == 2 || wv < 2) {
        const int c0 = wv * 16;         // < Ca guaranteed
        v4f acc2[2] = {z4, z4};
        #pragma unroll
        for (int k = 0; k < 16; k++) {
            v8s a0 = *(const v8s*)(s_h + li * 520 + k * 32 + lg * 8);
            v8s a1 = *(const v8s*)(s_h + (16 + li) * 520 + k * 32 + lg * 8);
            v8s b0 = *(const v8s*)(f2wb + (c0 + li) * 512 + k * 32 + lg * 8);
            acc2[0] = MFMA16(a0, b0, acc2[0]);
            acc2[1] = MFMA16(a1, b0, acc2[1]);
        }
        float bo0 = f2b[c0 + li];
        #pragma unroll
        for (int m = 0; m < 2; m++)
            #pragma unroll
            for (int r = 0; r < 4; r++)
                yacc[0][m][r] += wgt * (acc2[m][r] + bo0);
    }
}

__global__ __launch_bounds__(256, 3) void k_mlp(
    const unsigned short* __restrict__ xn,
    const unsigned short* __restrict__ f1wb, const float* __restrict__ f1b,
    const unsigned short* __restrict__ f2wb, const float* __restrict__ f2b,
    const float* __restrict__ gw, float* __restrict__ out) {

    __shared__ unsigned short s_h[32 * 520];   // hidden bf16 [32][520]

    const int tid = threadIdx.x, wv = tid >> 6, lane = tid & 63;
    const int li = lane & 15, lg = lane >> 4;
    const int t0 = blockIdx.x * 32;
    const bool sp = (t0 >= 100352);

    const v4f z4 = {0.f, 0.f, 0.f, 0.f};
    v4f yacc[2][2];
    #pragma unroll
    for (int n = 0; n < 2; n++)
        #pragma unroll
        for (int m = 0; m < 2; m++) yacc[n][m] = z4;

    // A-fragments of xn (pass-invariant): load once
    v8s ax[2][4];
    #pragma unroll
    for (int m = 0; m < 2; m++)
        #pragma unroll
        for (int k = 0; k < 4; k++)
            ax[m][k] = *(const v8s*)(xn + (size_t)(t0 + m * 16 + li) * 128 + k * 32 + lg * 8);

    if (sp) {
        mlp_pass<4>(ax, f1wb, f1b, f2wb, f2b, gw[0], wv, li, lg, s_h, yacc);
        __syncthreads();   // protect s_h overwrite vs fc2 reads
        mlp_pass<2>(ax, f1wb, f1b, f2wb, f2b, gw[1], wv, li, lg, s_h, yacc);
        __syncthreads();
        mlp_pass<1>(ax, f1wb, f1b, f2wb, f2b, gw[2], wv, li, lg, s_h, yacc);
    } else {
        mlp_pass<4>(ax, f1wb, f1b, f2wb, f2b, 1.f, wv, li, lg, s_h, yacc);
    }

    // ---- epilogue: stage y in LDS, then coalesced out += y ----
    __syncthreads();                     // fc2 reads of s_h complete
    float* s_y = (float*)s_h;            // [32][132] f32 = 16,896 B
    #pragma unroll
    for (int m = 0; m < 2; m++)
        #pragma unroll
        for (int r = 0; r < 4; r++) {
            int t = m * 16 + lg * 4 + r;
            #pragma unroll
            for (int nt = 0; nt < 2; nt++)
                s_y[t * 132 + (nt * 4 + wv) * 16 + li] = yacc[nt][m][r];
        }
    __syncthreads();

    const int rgrp = tid >> 5;           // 0..7
    const int col  = (tid & 31) * 4;     // 0..124
    #pragma unroll
    for (int it = 0; it < 4; it++) {
        int t = it * 8 + rgrp;
        size_t base = (size_t)(t0 + t) * 128 + col;
        v4f ov = *(const v4f*)(out + base);
        v4f yv = *(const v4f*)(s_y + t * 132 + col);
        *(v4f*)(out + base) = ov + yv;
    }
}

// ---------------------------------------------------------------------------
extern "C" void kernel_launch(void* const* d_in, const int* in_sizes, int n_in,
                              void* d_out, int out_size, void* d_ws, size_t ws_size,
                              hipStream_t stream) {
    const float* x      = (const float*)d_in[0];
    const float* gw     = (const float*)d_in[1];
    const float* n1w    = (const float*)d_in[2];
    const float* n1b    = (const float*)d_in[3];
    const float* qkvw   = (const float*)d_in[4];
    const float* qkvb   = (const float*)d_in[5];
    const float* rbt    = (const float*)d_in[6];
    const float* pw     = (const float*)d_in[7];
    const float* pb     = (const float*)d_in[8];
    const float* amask  = (const float*)d_in[9];
    const float* n2w    = (const float*)d_in[10];
    const float* n2b    = (const float*)d_in[11];
    const float* f1w    = (const float*)d_in[12];
    const float* f1b    = (const float*)d_in[13];
    const float* f2w    = (const float*)d_in[14];
    const float* f2b    = (const float*)d_in[15];
    const int*   relidx = (const int*)d_in[16];
    float* out = (float*)d_out;

    unsigned short* xw    = (unsigned short*)d_ws;
    float*          comb  = (float*)((char*)d_ws + WS_COMB);
    unsigned short* wqkv  = (unsigned short*)((char*)d_ws + WS_WQKV);
    unsigned short* wproj = (unsigned short*)((char*)d_ws + WS_WPROJ);
    unsigned short* f1wb  = (unsigned short*)((char*)d_ws + WS_F1W);
    unsigned short* f2wb  = (unsigned short*)((char*)d_ws + WS_F2W);
    unsigned short* xn    = (unsigned short*)d_ws;   // aliases xw (dead by then)

    hipLaunchKernelGGL(k_prep, dim3(8704), dim3(256), 0, stream,
                       amask, rbt, relidx, qkvw, pw, f1w, f2w,
                       comb, wqkv, wproj, f1wb, f2wb, xw);
    hipLaunchKernelGGL(k_ln1, dim3(NTOK / 4), dim3(256), 0, stream, x, n1w, n1b, xw);
    hipLaunchKernelGGL(k_attn, dim3(NWIN), dim3(256), 0, stream,
                       xw, wqkv, qkvb, comb, wproj, pb, gw, x, out);
    hipLaunchKernelGGL(k_ln2, dim3(NTOK / 4), dim3(256), 0, stream, out, n2w, n2b, xn);
    hipLaunchKernelGGL(k_mlp, dim3(NTOK / 32), dim3(256), 0, stream,
                       xn, f1wb, f1b, f2wb, f2b, gw, out);
}

// Round 7
// 726.251 us; speedup vs baseline: 1.3742x; 1.0720x over previous
//
#include <hip/hip_runtime.h>
#include <hip/hip_bf16.h>

// Problem constants
#define SHIFT_ 3
#define SCALE_ 0.17677669529663687f   // 32^-0.5
#define NTOK   200704                 // 64*56*56
#define NWIN   4096

typedef short v8s __attribute__((ext_vector_type(8)));
typedef float v4f __attribute__((ext_vector_type(4)));
#define MFMA16(a, b, c) __builtin_amdgcn_mfma_f32_16x16x32_bf16(a, b, c, 0, 0, 0)

static __device__ __forceinline__ unsigned short f2bf(float f) {
    union { float f; unsigned int u; } v; v.f = f;
    unsigned int u = v.u;
    unsigned int r = u + 0x7FFFu + ((u >> 16) & 1u);   // RNE
    return (unsigned short)(r >> 16);
}
// tanh-form GELU in sigmoid shape: v*sigmoid(1.5957691*(v+0.044715 v^3)).
static __device__ __forceinline__ float gelu_f(float v) {
    float w = v * v;
    float t = v * fmaf(w, 0.07135481283f, 1.595769122f);
    float e = __expf(-t);
    return v * __builtin_amdgcn_rcpf(1.f + e);
}

// ws layout (bytes):
//   0        : xn bf16 [200704 tok][128]  (written by k_attn epilogue)
//   67108864 : comb f32 [64][4][64][64]
//   71303168 : wqkv bf16 [384][128]
//   71401472 : wproj bf16 [128][128]
//   71434240 : f1w bf16 [512][128]
//   71565312 : f2w bf16 [128][512]
#define WS_COMB  67108864
#define WS_WQKV  71303168
#define WS_WPROJ 71401472
#define WS_F1W   71434240
#define WS_F2W   71565312

// ---------------------------------------------------------------------------
// K0: prep — comb table + bf16 weight conversion (xw staging removed).
// ---------------------------------------------------------------------------
__global__ __launch_bounds__(256) void k_prep(
    const float* __restrict__ amask, const float* __restrict__ rbt,
    const int* __restrict__ relidx,
    const float* __restrict__ qkvw, const float* __restrict__ projw,
    const float* __restrict__ f1w, const float* __restrict__ f2w,
    float* __restrict__ comb, unsigned short* __restrict__ wqkv,
    unsigned short* __restrict__ wproj, unsigned short* __restrict__ f1wb,
    unsigned short* __restrict__ f2wb) {
    int idx = blockIdx.x * 256 + threadIdx.x;
    if (idx < 1048576) {
        int wpos = idx >> 14;
        int h = (idx >> 12) & 3;
        int i = (idx >> 6) & 63;
        int j = idx & 63;
        float v;
        if (j >= 49) v = -1e30f;
        else if (i >= 49) v = 0.f;
        else v = amask[wpos * 2401 + i * 49 + j] + rbt[relidx[i * 49 + j] * 4 + h];
        comb[idx] = v;
    } else if (idx < 1048576 + 49152) {
        int k = idx - 1048576; wqkv[k] = f2bf(qkvw[k]);
    } else if (idx < 1048576 + 49152 + 16384) {
        int k = idx - (1048576 + 49152); wproj[k] = f2bf(projw[k]);
    } else if (idx < 1048576 + 49152 + 16384 + 65536) {
        int k = idx - (1048576 + 49152 + 16384); f1wb[k] = f2bf(f1w[k]);
    } else if (idx < 1048576 + 49152 + 16384 + 65536 + 65536) {
        int k = idx - (1048576 + 49152 + 16384 + 65536); f2wb[k] = f2bf(f2w[k]);
    }
}

// ---------------------------------------------------------------------------
// K2: MFMA window attention. Pass structure as R3/R6 (verified). New:
//   prologue = fused LN1 + roll + partition (x -> s_x bf16 in LDS)
//   epilogue = residual + fused LN2 (writes out f32 AND xn bf16)
// ---------------------------------------------------------------------------
template<int KA>
__device__ __forceinline__ void attn_pass(
    const v8s (&ax)[4][4],
    const unsigned short* __restrict__ wqkv, const float* __restrict__ qkvb,
    const float* __restrict__ comb,
    const unsigned short* __restrict__ wproj, const float* __restrict__ pbias,
    float wgt, int wpos, int wv, int li, int lg,
    unsigned short* __restrict__ s_q, unsigned short* __restrict__ s_k,
    unsigned short* __restrict__ s_v, unsigned short* __restrict__ pw_,
    v4f (&yacc)[2][4])
{
    const v4f z4 = {0.f, 0.f, 0.f, 0.f};
    constexpr int Ca = KA * 32;

    // ---- QKV (n-split): wave handles cols [wv*96, wv*96+96) of 384 ----
    #pragma unroll 2
    for (int nt = 0; nt < 6; nt++) {
        const int ntg = wv * 6 + nt, o0 = ntg * 16;
        v4f acc[4] = {z4, z4, z4, z4};
        #pragma unroll
        for (int k = 0; k < KA; k++) {
            v8s b = *(const v8s*)(wqkv + (o0 + li) * 128 + k * 32 + lg * 8);
            #pragma unroll
            for (int m = 0; m < 4; m++) acc[m] = MFMA16(ax[m][k], b, acc[m]);
        }
        float bo = qkvb[o0 + li];
        if (ntg < 16) {              // q or k, token-major [64][136]
            unsigned short* dst = (ntg < 8) ? s_q : s_k;
            const int oc = (ntg < 8) ? o0 : o0 - 128;
            const float scl = (ntg < 8) ? SCALE_ : 1.f;
            #pragma unroll
            for (int m = 0; m < 4; m++)
                #pragma unroll
                for (int r = 0; r < 4; r++)
                    dst[(m * 16 + lg * 4 + r) * 136 + oc + li] =
                        f2bf((acc[m][r] + bo) * scl);
        } else {                     // v transposed: vT[d][t], [128][72]
            const int d = (ntg - 16) * 16 + li;
            #pragma unroll
            for (int m = 0; m < 4; m++) {
                int t0_ = m * 16 + lg * 4;
                unsigned int p0 = (unsigned int)f2bf(acc[m][0] + bo) |
                                  ((unsigned int)f2bf(acc[m][1] + bo) << 16);
                unsigned int p1 = (unsigned int)f2bf(acc[m][2] + bo) |
                                  ((unsigned int)f2bf(acc[m][3] + bo) << 16);
                *(unsigned int*)(s_v + d * 72 + t0_)     = p0;
                *(unsigned int*)(s_v + d * 72 + t0_ + 2) = p1;
            }
        }
    }
    __syncthreads();   // s1: q,k,vT visible

    // ---- heads (m-split): wave owns query rows [wv*16, wv*16+16) ----
    v4f oacc[8];
    #pragma unroll
    for (int i = 0; i < 8; i++) oacc[i] = z4;
    #pragma unroll
    for (int h = 0; h < 4; h++) {
        v8s aq = *(const v8s*)(s_q + (wv * 16 + li) * 136 + h * 32 + lg * 8);
        v4f sc[4];
        #pragma unroll
        for (int ntj = 0; ntj < 4; ntj++) {
            v8s bk = *(const v8s*)(s_k + (ntj * 16 + li) * 136 + h * 32 + lg * 8);
            sc[ntj] = MFMA16(aq, bk, z4);
        }
        const float* cb = comb + ((size_t)(wpos * 4 + h) << 12) + (wv * 16 + lg * 4) * 64;
        #pragma unroll
        for (int r = 0; r < 4; r++) {
            float vmax = -3.0e38f, e[4];
            #pragma unroll
            for (int ntj = 0; ntj < 4; ntj++) {
                float v_ = sc[ntj][r] + cb[r * 64 + ntj * 16 + li];
                sc[ntj][r] = v_;
                vmax = fmaxf(vmax, v_);
            }
            #pragma unroll
            for (int o_ = 1; o_ < 16; o_ <<= 1) vmax = fmaxf(vmax, __shfl_xor(vmax, o_));
            float ssum = 0.f;
            #pragma unroll
            for (int ntj = 0; ntj < 4; ntj++) {
                e[ntj] = __expf(sc[ntj][r] - vmax);
                ssum += e[ntj];
            }
            #pragma unroll
            for (int o_ = 1; o_ < 16; o_ <<= 1) ssum += __shfl_xor(ssum, o_);
            float inv = __builtin_amdgcn_rcpf(ssum);
            #pragma unroll
            for (int ntj = 0; ntj < 4; ntj++)
                pw_[(lg * 4 + r) * 72 + ntj * 16 + li] = f2bf(e[ntj] * inv);
        }
        // PV: O[t][h*32+d] += P @ V
        #pragma unroll
        for (int k0 = 0; k0 < 2; k0++) {
            v8s ap = *(const v8s*)(pw_ + li * 72 + k0 * 32 + lg * 8);
            #pragma unroll
            for (int dn = 0; dn < 2; dn++) {
                v8s bv = *(const v8s*)(s_v + (h * 32 + dn * 16 + li) * 72 + k0 * 32 + lg * 8);
                oacc[h * 2 + dn] = MFMA16(ap, bv, oacc[h * 2 + dn]);
            }
        }
    }
    __syncthreads();   // s2: all waves done reading s_k/s_v/s_q

    // ---- o -> LDS (reuse s_k region), token-major [64][136] ----
    unsigned short* s_o = s_k;
    #pragma unroll
    for (int ot = 0; ot < 8; ot++)
        #pragma unroll
        for (int r = 0; r < 4; r++)
            s_o[(wv * 16 + lg * 4 + r) * 136 + ot * 16 + li] = f2bf(oacc[ot][r]);
    __syncthreads();   // s3: o visible

    // ---- proj (n-split, interleaved tiles (nt*4+wv)*16, compile-time mask) ----
    if (KA == 4 || wv * 16 < Ca) {
        v8s ao[4][4];
        #pragma unroll
        for (int m = 0; m < 4; m++)
            #pragma unroll
            for (int k = 0; k < 4; k++)
                ao[m][k] = *(const v8s*)(s_o + (m * 16 + li) * 136 + k * 32 + lg * 8);
        #pragma unroll
        for (int nt = 0; nt < 2; nt++) {
            const int co0 = (nt * 4 + wv) * 16;
            if (nt == 0 || Ca == 128) {
                if (co0 < Ca) {
                    v4f pacc[4] = {z4, z4, z4, z4};
                    #pragma unroll
                    for (int k = 0; k < 4; k++) {
                        v8s b = *(const v8s*)(wproj + (co0 + li) * 128 + k * 32 + lg * 8);
                        #pragma unroll
                        for (int m = 0; m < 4; m++) pacc[m] = MFMA16(ao[m][k], b, pacc[m]);
                    }
                    float bo = pbias[co0 + li];
                    #pragma unroll
                    for (int m = 0; m < 4; m++)
                        #pragma unroll
                        for (int r = 0; r < 4; r++)
                            yacc[nt][m][r] += wgt * (pacc[m][r] + bo);
                }
            }
        }
    }
    __syncthreads();   // s4: end of pass (protects s_q/s_k/s_v reuse)
}

__global__ __launch_bounds__(256, 2) void k_attn(
    const unsigned short* __restrict__ wqkv, const float* __restrict__ qkvb,
    const float* __restrict__ comb,
    const unsigned short* __restrict__ wproj, const float* __restrict__ pbias,
    const float* __restrict__ gw,
    const float* __restrict__ x,
    const float* __restrict__ n1w, const float* __restrict__ n1b,
    const float* __restrict__ n2w, const float* __restrict__ n2b,
    float* __restrict__ out, unsigned short* __restrict__ xn) {

    __shared__ unsigned short sm[31232];
    unsigned short* s_q = sm;            // [64][136]  (s_x during prologue)
    unsigned short* s_k = sm + 8704;     // [64][136], later o
    unsigned short* s_v = sm + 17408;    // vT [128][72]
    unsigned short* s_p = sm + 26624;    // 4 x [16][72]

    const int tid = threadIdx.x, wv = tid >> 6, lane = tid & 63;
    const int li = lane & 15, lg = lane >> 4;
    const int w = blockIdx.x;
    const int wpos = w & 63;
    const bool sp = (w >= 2048);
    const int bb = w >> 6, wh = (w >> 3) & 7, ww = w & 7;
    unsigned short* pw_ = s_p + wv * 1152;

    // ---- prologue: fused LN1 + roll(-3,-3) + partition -> s_x bf16 [64][136]
    {
        unsigned short* s_x = s_q;
        float4 g0 = *(const float4*)(n1w + li * 8);
        float4 g1 = *(const float4*)(n1w + li * 8 + 4);
        float4 c0 = *(const float4*)(n1b + li * 8);
        float4 c1 = *(const float4*)(n1b + li * 8 + 4);
        #pragma unroll
        for (int bq = 0; bq < 4; bq++) {
            int t = wv * 16 + bq * 4 + lg;     // 4 tokens per wave in parallel
            float4 xa = {0.f, 0.f, 0.f, 0.f}, xb = {0.f, 0.f, 0.f, 0.f};
            if (t < 49) {
                int ti = t / 7, tj = t - ti * 7;
                int h2 = wh * 7 + ti + SHIFT_; if (h2 >= 56) h2 -= 56;
                int w2 = ww * 7 + tj + SHIFT_; if (w2 >= 56) w2 -= 56;
                const float* src = x + ((size_t)bb * 3136 + h2 * 56 + w2) * 128 + li * 8;
                xa = *(const float4*)src;
                xb = *(const float4*)(src + 4);
            }
            float s  = xa.x + xa.y + xa.z + xa.w + xb.x + xb.y + xb.z + xb.w;
            float sq = xa.x*xa.x + xa.y*xa.y + xa.z*xa.z + xa.w*xa.w
                     + xb.x*xb.x + xb.y*xb.y + xb.z*xb.z + xb.w*xb.w;
            #pragma unroll
            for (int o_ = 1; o_ < 16; o_ <<= 1) {
                s  += __shfl_xor(s, o_);
                sq += __shfl_xor(sq, o_);
            }
            float mu  = s * (1.f / 128.f);
            float var = sq * (1.f / 128.f) - mu * mu;
            float inv = rsqrtf(var + 1e-5f);
            uint4 P = make_uint4(0u, 0u, 0u, 0u);
            if (t < 49) {
                float y0 = (xa.x - mu) * inv * g0.x + c0.x;
                float y1 = (xa.y - mu) * inv * g0.y + c0.y;
                float y2 = (xa.z - mu) * inv * g0.z + c0.z;
                float y3 = (xa.w - mu) * inv * g0.w + c0.w;
                float y4 = (xb.x - mu) * inv * g1.x + c1.x;
                float y5 = (xb.y - mu) * inv * g1.y + c1.y;
                float y6 = (xb.z - mu) * inv * g1.z + c1.z;
                float y7 = (xb.w - mu) * inv * g1.w + c1.w;
                P.x = (unsigned int)f2bf(y0) | ((unsigned int)f2bf(y1) << 16);
                P.y = (unsigned int)f2bf(y2) | ((unsigned int)f2bf(y3) << 16);
                P.z = (unsigned int)f2bf(y4) | ((unsigned int)f2bf(y5) << 16);
                P.w = (unsigned int)f2bf(y6) | ((unsigned int)f2bf(y7) << 16);
            }
            *(uint4*)(s_x + (size_t)t * 136 + li * 8) = P;   // zeros for pad rows
        }
    }
    __syncthreads();   // s_x complete

    const v4f z4 = {0.f, 0.f, 0.f, 0.f};
    v4f yacc[2][4];
    #pragma unroll
    for (int n = 0; n < 2; n++)
        #pragma unroll
        for (int m = 0; m < 4; m++) yacc[n][m] = z4;

    // A-fragments (pass-invariant): load once from s_x
    v8s ax[4][4];
    #pragma unroll
    for (int m = 0; m < 4; m++)
        #pragma unroll
        for (int k = 0; k < 4; k++)
            ax[m][k] = *(const v8s*)(s_q + (m * 16 + li) * 136 + k * 32 + lg * 8);
    __syncthreads();   // s_x consumed; passes may overwrite s_q

    if (sp) {
        attn_pass<4>(ax, wqkv, qkvb, comb, wproj, pbias, gw[0], wpos, wv, li, lg,
                     s_q, s_k, s_v, pw_, yacc);
        attn_pass<2>(ax, wqkv, qkvb, comb, wproj, pbias, gw[1], wpos, wv, li, lg,
                     s_q, s_k, s_v, pw_, yacc);
        attn_pass<1>(ax, wqkv, qkvb, comb, wproj, pbias, gw[2], wpos, wv, li, lg,
                     s_q, s_k, s_v, pw_, yacc);
    } else {
        attn_pass<4>(ax, wqkv, qkvb, comb, wproj, pbias, 1.f, wpos, wv, li, lg,
                     s_q, s_k, s_v, pw_, yacc);
    }

    // ---- epilogue: stage y in LDS; coalesced residual write + fused LN2 ----
    float* s_y = (float*)sm;             // [64][132] f32 = 33,792 B
    #pragma unroll
    for (int m = 0; m < 4; m++)
        #pragma unroll
        for (int r = 0; r < 4; r++) {
            int t = m * 16 + lg * 4 + r;
            #pragma unroll
            for (int nt = 0; nt < 2; nt++)
                s_y[t * 132 + (nt * 4 + wv) * 16 + li] = yacc[nt][m][r];
        }
    __syncthreads();

    const int rgrp = tid >> 5;           // 0..7 (half-wave id)
    const int col  = (tid & 31) * 4;     // 0..124
    float4 g2 = *(const float4*)(n2w + col);
    float4 c2 = *(const float4*)(n2b + col);
    #pragma unroll
    for (int it = 0; it < 7; it++) {
        int t = it * 8 + rgrp;
        if (t < 49) {
            int ti = t / 7, tj = t - ti * 7;
            int h2 = wh * 7 + ti + SHIFT_; if (h2 >= 56) h2 -= 56;
            int w2 = ww * 7 + tj + SHIFT_; if (w2 >= 56) w2 -= 56;
            size_t tok  = (size_t)bb * 3136 + h2 * 56 + w2;
            size_t base = tok * 128 + col;
            v4f xv = *(const v4f*)(x + base);
            v4f yv = *(const v4f*)(s_y + t * 132 + col);
            v4f ov = xv + yv;
            *(v4f*)(out + base) = ov;
            // fused LN2 over the 128 channels held by this 32-lane half-wave
            float s  = ov[0] + ov[1] + ov[2] + ov[3];
            float sq = ov[0]*ov[0] + ov[1]*ov[1] + ov[2]*ov[2] + ov[3]*ov[3];
            #pragma unroll
            for (int o_ = 1; o_ < 32; o_ <<= 1) {
                s  += __shfl_xor(s, o_);
                sq += __shfl_xor(sq, o_);
            }
            float mu  = s * (1.f / 128.f);
            float var = sq * (1.f / 128.f) - mu * mu;
            float inv = rsqrtf(var + 1e-5f);
            unsigned int q0 = (unsigned int)f2bf((ov[0] - mu) * inv * g2.x + c2.x) |
                              ((unsigned int)f2bf((ov[1] - mu) * inv * g2.y + c2.y) << 16);
            unsigned int q1 = (unsigned int)f2bf((ov[2] - mu) * inv * g2.z + c2.z) |
                              ((unsigned int)f2bf((ov[3] - mu) * inv * g2.w + c2.w) << 16);
            uint2 Q; Q.x = q0; Q.y = q1;
            *(uint2*)(xn + tok * 128 + col) = Q;
        }
    }
}

// ---------------------------------------------------------------------------
// K4: MFMA MLP — R3/R6-verified allocation point (VGPR 64, zero spill).
// ---------------------------------------------------------------------------
template<int KA>
__device__ __forceinline__ void mlp_pass(
    const v8s (&ax)[2][4],
    const unsigned short* __restrict__ f1wb, const float* __restrict__ f1b,
    const unsigned short* __restrict__ f2wb, const float* __restrict__ f2b,
    float wgt, int wv, int li, int lg,
    unsigned short* __restrict__ s_h, v4f (&yacc)[2][2])
{
    const v4f z4 = {0.f, 0.f, 0.f, 0.f};
    constexpr int Ca = KA * 32;

    // fc1 (n-split: wave cols [wv*128, wv*128+128)) + GELU -> s_h bf16
    #pragma unroll 4
    for (int nt = 0; nt < 8; nt++) {
        const int o0 = wv * 128 + nt * 16;
        v4f acc[2] = {z4, z4};
        #pragma unroll
        for (int k = 0; k < KA; k++) {
            v8s b = *(const v8s*)(f1wb + (o0 + li) * 128 + k * 32 + lg * 8);
            acc[0] = MFMA16(ax[0][k], b, acc[0]);
            acc[1] = MFMA16(ax[1][k], b, acc[1]);
        }
        float bo = f1b[o0 + li];
        #pragma unroll
        for (int m = 0; m < 2; m++)
            #pragma unroll
            for (int r = 0; r < 4; r++) {
                float v_ = gelu_f(acc[m][r] + bo);
                s_h[(m * 16 + lg * 4 + r) * 520 + o0 + li] = f2bf(v_);
            }
    }
    __syncthreads();

    // fc2: tiles co0 = wv*16 and 64+wv*16, compile-time masked, K=512 unrolled
    if (KA == 4) {
        const int c0 = wv * 16, c1 = 64 + wv * 16;
        v4f acc2[2][2] = {{z4, z4}, {z4, z4}};
        #pragma unroll
        for (int k = 0; k < 16; k++) {
            v8s a0 = *(const v8s*)(s_h + li * 520 + k * 32 + lg * 8);
            v8s a1 = *(const v8s*)(s_h + (16 + li) * 520 + k * 32 + lg * 8);
            v8s b0 = *(const v8s*)(f2wb + (c0 + li) * 512 + k * 32 + lg * 8);
            v8s b1 = *(const v8s*)(f2wb + (c1 + li) * 512 + k * 32 + lg * 8);
            acc2[0][0] = MFMA16(a0, b0, acc2[0][0]);
            acc2[0][1] = MFMA16(a1, b0, acc2[0][1]);
            acc2[1][0] = MFMA16(a0, b1, acc2[1][0]);
            acc2[1][1] = MFMA16(a1, b1, acc2[1][1]);
        }
        float bo0 = f2b[c0 + li], bo1 = f2b[c1 + li];
        #pragma unroll
        for (int m = 0; m < 2; m++)
            #pragma unroll
            for (int r = 0; r < 4; r++) {
                yacc[0][m][r] += wgt * (acc2[0][m][r] + bo0);
                yacc[1][m][r] += wgt * (acc2[1][m][r] + bo1);
            }
    } else if (KA == 2 || wv < 2) {
        const int c0 = wv * 16;         // < Ca guaranteed
        v4f acc2[2] = {z4, z4};
        #pragma unroll
        for (int k = 0; k < 16; k++) {
            v8s a0 = *(const v8s*)(s_h + li * 520 + k * 32 + lg * 8);
            v8s a1 = *(const v8s*)(s_h + (16 + li) * 520 + k * 32 + lg * 8);
            v8s b0 = *(const v8s*)(f2wb + (c0 + li) * 512 + k * 32 + lg * 8);
            acc2[0] = MFMA16(a0, b0, acc2[0]);
            acc2[1] = MFMA16(a1, b0, acc2[1]);
        }
        float bo0 = f2b[c0 + li];
        #pragma unroll
        for (int m = 0; m < 2; m++)
            #pragma unroll
            for (int r = 0; r < 4; r++)
                yacc[0][m][r] += wgt * (acc2[m][r] + bo0);
    }
}

__global__ __launch_bounds__(256, 3) void k_mlp(
    const unsigned short* __restrict__ xn,
    const unsigned short* __restrict__ f1wb, const float* __restrict__ f1b,
    const unsigned short* __restrict__ f2wb, const float* __restrict__ f2b,
    const float* __restrict__ gw, float* __restrict__ out) {

    __shared__ unsigned short s_h[32 * 520];   // hidden bf16 [32][520]

    const int tid = threadIdx.x, wv = tid >> 6, lane = tid & 63;
    const int li = lane & 15, lg = lane >> 4;
    const int t0 = blockIdx.x * 32;
    const bool sp = (t0 >= 100352);

    const v4f z4 = {0.f, 0.f, 0.f, 0.f};
    v4f yacc[2][2];
    #pragma unroll
    for (int n = 0; n < 2; n++)
        #pragma unroll
        for (int m = 0; m < 2; m++) yacc[n][m] = z4;

    // A-fragments of xn (pass-invariant): load once
    v8s ax[2][4];
    #pragma unroll
    for (int m = 0; m < 2; m++)
        #pragma unroll
        for (int k = 0; k < 4; k++)
            ax[m][k] = *(const v8s*)(xn + (size_t)(t0 + m * 16 + li) * 128 + k * 32 + lg * 8);

    if (sp) {
        mlp_pass<4>(ax, f1wb, f1b, f2wb, f2b, gw[0], wv, li, lg, s_h, yacc);
        __syncthreads();   // protect s_h overwrite vs fc2 reads
        mlp_pass<2>(ax, f1wb, f1b, f2wb, f2b, gw[1], wv, li, lg, s_h, yacc);
        __syncthreads();
        mlp_pass<1>(ax, f1wb, f1b, f2wb, f2b, gw[2], wv, li, lg, s_h, yacc);
    } else {
        mlp_pass<4>(ax, f1wb, f1b, f2wb, f2b, 1.f, wv, li, lg, s_h, yacc);
    }

    // ---- epilogue: stage y in LDS, then coalesced out += y ----
    __syncthreads();                     // fc2 reads of s_h complete
    float* s_y = (float*)s_h;            // [32][132] f32 = 16,896 B
    #pragma unroll
    for (int m = 0; m < 2; m++)
        #pragma unroll
        for (int r = 0; r < 4; r++) {
            int t = m * 16 + lg * 4 + r;
            #pragma unroll
            for (int nt = 0; nt < 2; nt++)
                s_y[t * 132 + (nt * 4 + wv) * 16 + li] = yacc[nt][m][r];
        }
    __syncthreads();

    const int rgrp = tid >> 5;           // 0..7
    const int col  = (tid & 31) * 4;     // 0..124
    #pragma unroll
    for (int it = 0; it < 4; it++) {
        int t = it * 8 + rgrp;
        size_t base = (size_t)(t0 + t) * 128 + col;
        v4f ov = *(const v4f*)(out + base);
        v4f yv = *(const v4f*)(s_y + t * 132 + col);
        *(v4f*)(out + base) = ov + yv;
    }
}

// ---------------------------------------------------------------------------
extern "C" void kernel_launch(void* const* d_in, const int* in_sizes, int n_in,
                              void* d_out, int out_size, void* d_ws, size_t ws_size,
                              hipStream_t stream) {
    const float* x      = (const float*)d_in[0];
    const float* gw     = (const float*)d_in[1];
    const float* n1w    = (const float*)d_in[2];
    const float* n1b    = (const float*)d_in[3];
    const float* qkvw   = (const float*)d_in[4];
    const float* qkvb   = (const float*)d_in[5];
    const float* rbt    = (const float*)d_in[6];
    const float* pw     = (const float*)d_in[7];
    const float* pb     = (const float*)d_in[8];
    const float* amask  = (const float*)d_in[9];
    const float* n2w    = (const float*)d_in[10];
    const float* n2b    = (const float*)d_in[11];
    const float* f1w    = (const float*)d_in[12];
    const float* f1b    = (const float*)d_in[13];
    const float* f2w    = (const float*)d_in[14];
    const float* f2b    = (const float*)d_in[15];
    const int*   relidx = (const int*)d_in[16];
    float* out = (float*)d_out;

    unsigned short* xn    = (unsigned short*)d_ws;
    float*          comb  = (float*)((char*)d_ws + WS_COMB);
    unsigned short* wqkv  = (unsigned short*)((char*)d_ws + WS_WQKV);
    unsigned short* wproj = (unsigned short*)((char*)d_ws + WS_WPROJ);
    unsigned short* f1wb  = (unsigned short*)((char*)d_ws + WS_F1W);
    unsigned short* f2wb  = (unsigned short*)((char*)d_ws + WS_F2W);

    hipLaunchKernelGGL(k_prep, dim3(4864), dim3(256), 0, stream,
                       amask, rbt, relidx, qkvw, pw, f1w, f2w,
                       comb, wqkv, wproj, f1wb, f2wb);
    hipLaunchKernelGGL(k_attn, dim3(NWIN), dim3(256), 0, stream,
                       wqkv, qkvb, comb, wproj, pb, gw, x,
                       n1w, n1b, n2w, n2b, out, xn);
    hipLaunchKernelGGL(k_mlp, dim3(NTOK / 32), dim3(256), 0, stream,
                       xn, f1wb, f1b, f2wb, f2b, gw, out);
}